// Round 1
// baseline (1043.347 us; speedup 1.0000x reference)
//
#include <hip/hip_runtime.h>
#include <math.h>
#include <stdint.h>

// ---------------------------------------------------------------------------
// QuantizedLinear: out = x @ quantize(w)^T + bias
//   quantize(w) = clip(round(w/(mean|w|+eps)*h), -h, h),  h=(2^1.58-1)/2
//   Ternary trick: qw ∈ {-h,0,+h} -> store t ∈ {-1,0,+1} as EXACT bf16,
//   scale by h (fp32) in GEMM epilogue. Only x suffers bf16 rounding.
// Shapes: x[16384,4096] (M,K) fp32, w[4096,4096] (N,K) fp32, bias[4096],
//         out[16384,4096] fp32.  NT GEMM (both operands K-contiguous).
// ---------------------------------------------------------------------------

#define MDIM 16384
#define NDIM 4096
#define KDIM 4096

// ---------------- reduction: sum |w| in double ----------------
__global__ void absmean_reduce(const float4* __restrict__ w4,
                               double* __restrict__ gsum, int n4) {
  int tid = blockIdx.x * blockDim.x + threadIdx.x;
  int stride = gridDim.x * blockDim.x;
  double s = 0.0;
  for (int i = tid; i < n4; i += stride) {
    float4 v = w4[i];
    s += (double)fabsf(v.x) + (double)fabsf(v.y) +
         (double)fabsf(v.z) + (double)fabsf(v.w);
  }
  // wave(64) shuffle reduce
  for (int off = 32; off > 0; off >>= 1) s += __shfl_down(s, off, 64);
  __shared__ double partial[4];
  int ln = threadIdx.x & 63, wv = threadIdx.x >> 6;
  if (ln == 0) partial[wv] = s;
  __syncthreads();
  if (threadIdx.x == 0) {
    double t = partial[0] + partial[1] + partial[2] + partial[3];
    atomicAdd(gsum, t);  // fp64 atomic: supported on gfx950
  }
}

// ---------------- quantize w -> ternary bf16 {-1,0,+1} ----------------
__device__ __forceinline__ unsigned short tern_bf16(float w, float g, float h) {
  float q = rintf(w / g * h);             // RNE, matches jnp.round; fp32 div like np
  q = fminf(fmaxf(q, -1.0f), 1.0f);       // {-2..2} -> {-1,0,1}
  return (unsigned short)(__float_as_uint(q) >> 16);  // ±1.0/±0.0 exact in bf16
}

__global__ void quantize_w(const float4* __restrict__ w4,
                           const double* __restrict__ gsum,
                           ushort4* __restrict__ wq, int n4, float halfF) {
  const float gamma = (float)(*gsum * (1.0 / 16777216.0)) + 1e-8f;
  int tid = blockIdx.x * blockDim.x + threadIdx.x;
  int stride = gridDim.x * blockDim.x;
  for (int i = tid; i < n4; i += stride) {
    float4 v = w4[i];
    ushort4 o;
    o.x = tern_bf16(v.x, gamma, halfF);
    o.y = tern_bf16(v.y, gamma, halfF);
    o.z = tern_bf16(v.z, gamma, halfF);
    o.w = tern_bf16(v.w, gamma, halfF);
    wq[i] = o;
  }
}

// ---------------- convert x fp32 -> bf16 (RNE) ----------------
__device__ __forceinline__ unsigned bf16_rne(float f) {
  unsigned u = __float_as_uint(f);
  return (u + 0x7FFFu + ((u >> 16) & 1u)) >> 16;
}
__device__ __forceinline__ unsigned pack2(float lo, float hi) {
  return bf16_rne(lo) | (bf16_rne(hi) << 16);
}

__global__ void cvt_x(const float4* __restrict__ x4, uint4* __restrict__ xb,
                      int n8) {
  int tid = blockIdx.x * blockDim.x + threadIdx.x;
  int stride = gridDim.x * blockDim.x;
  for (int i = tid; i < n8; i += stride) {
    float4 a = x4[2 * i];
    float4 b = x4[2 * i + 1];
    uint4 o;
    o.x = pack2(a.x, a.y);
    o.y = pack2(a.z, a.w);
    o.z = pack2(b.x, b.y);
    o.w = pack2(b.z, b.w);
    xb[i] = o;
  }
}

// ---------------- GEMM: m97 structure (128x128 tile, BK=64) ----------------
typedef __attribute__((ext_vector_type(8))) short bf16x8;  // 8 bf16 = 4 VGPRs
typedef __attribute__((ext_vector_type(4))) float f32x4;

#define BM 128
#define BN 128
#define BK 64

__device__ __forceinline__ void async16(const short* g, short* l) {
  // 16 B/lane global->LDS DMA; LDS dest = wave-uniform base + lane*16
  __builtin_amdgcn_global_load_lds(
      (const __attribute__((address_space(1))) unsigned int*)g,
      (__attribute__((address_space(3))) unsigned int*)l, 16, 0, 0);
}

__global__ __launch_bounds__(256, 2) void gemm_tern_bf16(
    const short* __restrict__ A,    // [M][K] bf16 bits (x)
    const short* __restrict__ Bw,   // [N][K] bf16 ternary (qw/h)
    const float* __restrict__ bias, // [N]
    float* __restrict__ out,        // [M][N] fp32
    float scale) {
  __shared__ short As[BM * BK];  // 16 KiB
  __shared__ short Bs[BN * BK];  // 16 KiB

  const int tid = threadIdx.x;
  const int wv = tid >> 6;        // wave 0..3
  const int ln = tid & 63;        // lane
  const int bm = blockIdx.y * BM;
  const int bn = blockIdx.x * BN;
  const int wm = (wv >> 1) * 64;  // wave quadrant inside tile
  const int wn = (wv & 1) * 64;

  f32x4 acc[4][4] = {};

  // staging: wave wv stages rows [wv*32, wv*32+32) of each tile,
  // 4 calls x 8 rows; lane l -> row +(l>>3), 16B chunk (l&7)
  const int srow = ln >> 3;
  const int scol = (ln & 7) * 8;
  const short* pA = A + (size_t)(bm + wv * 32 + srow) * KDIM + scol;
  const short* pB = Bw + (size_t)(bn + wv * 32 + srow) * KDIM + scol;

  for (int k0 = 0; k0 < KDIM; k0 += BK) {
#pragma unroll
    for (int c = 0; c < 4; ++c) {
      async16(pA + (size_t)(c * 8) * KDIM, As + (wv * 32 + c * 8) * BK);
      async16(pB + (size_t)(c * 8) * KDIM, Bs + (wv * 32 + c * 8) * BK);
    }
    pA += BK;
    pB += BK;
    __syncthreads();  // drains vmcnt for global_load_lds

#pragma unroll
    for (int ks = 0; ks < BK; ks += 32) {
      const int kk = ks + (ln >> 4) * 8;  // A[m=ln&15][k=quad*8+j]
      bf16x8 fa[4], fb[4];
#pragma unroll
      for (int t = 0; t < 4; ++t) {
        fa[t] = *(const bf16x8*)(As + (wm + t * 16 + (ln & 15)) * BK + kk);
        fb[t] = *(const bf16x8*)(Bs + (wn + t * 16 + (ln & 15)) * BK + kk);
      }
#pragma unroll
      for (int i = 0; i < 4; ++i)
#pragma unroll
        for (int j = 0; j < 4; ++j)
          acc[i][j] = __builtin_amdgcn_mfma_f32_16x16x32_bf16(
              fa[i], fb[j], acc[i][j], 0, 0, 0);
    }
    __syncthreads();
  }

  // epilogue: C/D layout col=ln&15, row=(ln>>4)*4+r  (m89-verified)
  const int col0 = bn + wn + (ln & 15);
  const int row0 = bm + wm + ((ln >> 4) << 2);
#pragma unroll
  for (int j = 0; j < 4; ++j) {
    const float bj = bias[col0 + j * 16];
#pragma unroll
    for (int i = 0; i < 4; ++i) {
#pragma unroll
      for (int r = 0; r < 4; ++r) {
        out[(size_t)(row0 + i * 16 + r) * NDIM + (col0 + j * 16)] =
            fmaf(acc[i][j][r], scale, bj);
      }
    }
  }
}

// ---------------- launch ----------------
extern "C" void kernel_launch(void* const* d_in, const int* in_sizes, int n_in,
                              void* d_out, int out_size, void* d_ws,
                              size_t ws_size, hipStream_t stream) {
  const float* x = (const float*)d_in[0];     // [16384*4096]
  const float* w = (const float*)d_in[1];     // [4096*4096]
  const float* bias = (const float*)d_in[2];  // [4096]
  float* out = (float*)d_out;

  // workspace layout
  char* ws = (char*)d_ws;
  double* gsum = (double*)ws;                       // 8 B
  short* xb = (short*)(ws + 256);                   // 134,217,728 B
  short* wq = (short*)(ws + 256 + (size_t)MDIM * KDIM * 2);  // 33,554,432 B

  const float kHalfF = (float)((pow(2.0, 1.58) - 1.0) * 0.5);  // 0.99484926f

  hipMemsetAsync(gsum, 0, sizeof(double), stream);

  const int nW4 = (NDIM * KDIM) / 4;  // 4,194,304
  absmean_reduce<<<1024, 256, 0, stream>>>((const float4*)w, gsum, nW4);

  quantize_w<<<4096, 256, 0, stream>>>((const float4*)w, gsum, (ushort4*)wq,
                                       nW4, kHalfF);

  const int nX8 = (MDIM * KDIM) / 8;  // 8,388,608
  cvt_x<<<8192, 256, 0, stream>>>((const float4*)x, (uint4*)xb, nX8);

  dim3 grid(NDIM / BN, MDIM / BM);  // 32 x 128
  gemm_tern_bf16<<<grid, 256, 0, stream>>>(xb, wq, bias, out, kHalfF);
}

// Round 2
// 990.831 us; speedup vs baseline: 1.0530x; 1.0530x over previous
//
#include <hip/hip_runtime.h>
#include <math.h>
#include <stdint.h>

// ---------------------------------------------------------------------------
// QuantizedLinear: out = x @ quantize(w)^T + bias
//   quantize(w) = clip(round(w/(mean|w|+eps)*h), -h, h),  h=(2^1.58-1)/2
//   Ternary trick: qw ∈ {-h,0,+h} -> store t ∈ {-1,0,+1} as EXACT bf16,
//   scale by h (fp32) in GEMM epilogue. Only x suffers bf16 rounding.
// Shapes: x[16384,4096] (M,K) fp32, w[4096,4096] (N,K) fp32, bias[4096],
//         out[16384,4096] fp32.  NT GEMM (both operands K-contiguous).
//
// R2: XOR-swizzled LDS layout. R1 had SQ_LDS_BANK_CONFLICT=2e8 (~12 cyc per
// ds_read_b128): LDS row stride 128 B = full bank wrap, so a quad's 16 lanes
// (16 rows, same column) serialized ~16-way. Swizzle: LDS slot (row,c) holds
// global chunk c^(row&7); reads use chunk ((ks/8)+(ln>>4))^(ln&7) -> 8
// distinct 4-bank groups per quad -> 2 lanes/bank (free, m136).
// ---------------------------------------------------------------------------

#define MDIM 16384
#define NDIM 4096
#define KDIM 4096

// ---------------- reduction: sum |w| in double ----------------
__global__ void absmean_reduce(const float4* __restrict__ w4,
                               double* __restrict__ gsum, int n4) {
  int tid = blockIdx.x * blockDim.x + threadIdx.x;
  int stride = gridDim.x * blockDim.x;
  double s = 0.0;
  for (int i = tid; i < n4; i += stride) {
    float4 v = w4[i];
    s += (double)fabsf(v.x) + (double)fabsf(v.y) +
         (double)fabsf(v.z) + (double)fabsf(v.w);
  }
  for (int off = 32; off > 0; off >>= 1) s += __shfl_down(s, off, 64);
  __shared__ double partial[4];
  int ln = threadIdx.x & 63, wv = threadIdx.x >> 6;
  if (ln == 0) partial[wv] = s;
  __syncthreads();
  if (threadIdx.x == 0) {
    double t = partial[0] + partial[1] + partial[2] + partial[3];
    atomicAdd(gsum, t);
  }
}

// ---------------- quantize w -> ternary bf16 {-1,0,+1} ----------------
__device__ __forceinline__ unsigned short tern_bf16(float w, float g, float h) {
  float q = rintf(w / g * h);             // RNE, matches jnp.round
  q = fminf(fmaxf(q, -1.0f), 1.0f);       // {-2..2} -> {-1,0,1}
  return (unsigned short)(__float_as_uint(q) >> 16);  // ±1.0/±0.0 exact bf16
}

__global__ void quantize_w(const float4* __restrict__ w4,
                           const double* __restrict__ gsum,
                           ushort4* __restrict__ wq, int n4, float halfF) {
  const float gamma = (float)(*gsum * (1.0 / 16777216.0)) + 1e-8f;
  int tid = blockIdx.x * blockDim.x + threadIdx.x;
  int stride = gridDim.x * blockDim.x;
  for (int i = tid; i < n4; i += stride) {
    float4 v = w4[i];
    ushort4 o;
    o.x = tern_bf16(v.x, gamma, halfF);
    o.y = tern_bf16(v.y, gamma, halfF);
    o.z = tern_bf16(v.z, gamma, halfF);
    o.w = tern_bf16(v.w, gamma, halfF);
    wq[i] = o;
  }
}

// ---------------- convert x fp32 -> bf16 (RNE) ----------------
__device__ __forceinline__ unsigned bf16_rne(float f) {
  unsigned u = __float_as_uint(f);
  return (u + 0x7FFFu + ((u >> 16) & 1u)) >> 16;
}
__device__ __forceinline__ unsigned pack2(float lo, float hi) {
  return bf16_rne(lo) | (bf16_rne(hi) << 16);
}

__global__ void cvt_x(const float4* __restrict__ x4, uint4* __restrict__ xb,
                      int n8) {
  int tid = blockIdx.x * blockDim.x + threadIdx.x;
  int stride = gridDim.x * blockDim.x;
  for (int i = tid; i < n8; i += stride) {
    float4 a = x4[2 * i];
    float4 b = x4[2 * i + 1];
    uint4 o;
    o.x = pack2(a.x, a.y);
    o.y = pack2(a.z, a.w);
    o.z = pack2(b.x, b.y);
    o.w = pack2(b.z, b.w);
    xb[i] = o;
  }
}

// ---------------- GEMM: 128x128 tile, BK=64, XOR-swizzled LDS ----------------
typedef __attribute__((ext_vector_type(8))) short bf16x8;  // 8 bf16 = 4 VGPRs
typedef __attribute__((ext_vector_type(4))) float f32x4;

#define BM 128
#define BN 128
#define BK 64

__device__ __forceinline__ void async16(const short* g, short* l) {
  __builtin_amdgcn_global_load_lds(
      (const __attribute__((address_space(1))) unsigned int*)g,
      (__attribute__((address_space(3))) unsigned int*)l, 16, 0, 0);
}

__global__ __launch_bounds__(256, 2) void gemm_tern_bf16(
    const short* __restrict__ A,    // [M][K] bf16 bits (x)
    const short* __restrict__ Bw,   // [N][K] bf16 ternary (qw/h)
    const float* __restrict__ bias, // [N]
    float* __restrict__ out,        // [M][N] fp32
    float scale) {
  __shared__ short As[BM * BK];  // 16 KiB
  __shared__ short Bs[BN * BK];  // 16 KiB

  const int tid = threadIdx.x;
  const int wv = tid >> 6;        // wave 0..3
  const int ln = tid & 63;        // lane
  const int bm = blockIdx.y * BM;
  const int bn = blockIdx.x * BN;
  const int wm = (wv >> 1) * 64;  // wave quadrant inside tile
  const int wn = (wv & 1) * 64;

  f32x4 acc[4][4] = {};

  // staging: wave wv stages rows [wv*32, wv*32+32), 4 calls x 8 rows.
  // lane l -> row +(l>>3); GLOBAL chunk ((l&7)^(l>>3)) lands in LDS slot
  // (l&7)  =>  LDS slot (row,c) holds global chunk c^(row&7).
  const int srow = ln >> 3;
  const int scol = ((ln & 7) ^ (ln >> 3)) * 8;  // swizzled global chunk
  const short* pA = A + (size_t)(bm + wv * 32 + srow) * KDIM + scol;
  const short* pB = Bw + (size_t)(bn + wv * 32 + srow) * KDIM + scol;

  for (int k0 = 0; k0 < KDIM; k0 += BK) {
#pragma unroll
    for (int c = 0; c < 4; ++c) {
      async16(pA + (size_t)(c * 8) * KDIM, As + (wv * 32 + c * 8) * BK);
      async16(pB + (size_t)(c * 8) * KDIM, Bs + (wv * 32 + c * 8) * BK);
    }
    pA += BK;
    pB += BK;
    __syncthreads();  // drains vmcnt for global_load_lds

#pragma unroll
    for (int ks = 0; ks < BK; ks += 32) {
      // logical chunk = ks/8 + (ln>>4); swizzled by ^(row&7), row&7 = ln&7
      const int ch = ((ks >> 3) + (ln >> 4)) ^ (ln & 7);
      bf16x8 fa[4], fb[4];
#pragma unroll
      for (int t = 0; t < 4; ++t) {
        fa[t] = *(const bf16x8*)(As + (wm + t * 16 + (ln & 15)) * BK + ch * 8);
        fb[t] = *(const bf16x8*)(Bs + (wn + t * 16 + (ln & 15)) * BK + ch * 8);
      }
#pragma unroll
      for (int i = 0; i < 4; ++i)
#pragma unroll
        for (int j = 0; j < 4; ++j)
          acc[i][j] = __builtin_amdgcn_mfma_f32_16x16x32_bf16(
              fa[i], fb[j], acc[i][j], 0, 0, 0);
    }
    __syncthreads();
  }

  // epilogue: C/D layout col=ln&15, row=(ln>>4)*4+r  (m89-verified)
  const int col0 = bn + wn + (ln & 15);
  const int row0 = bm + wm + ((ln >> 4) << 2);
#pragma unroll
  for (int j = 0; j < 4; ++j) {
    const float bj = bias[col0 + j * 16];
#pragma unroll
    for (int i = 0; i < 4; ++i) {
#pragma unroll
      for (int r = 0; r < 4; ++r) {
        out[(size_t)(row0 + i * 16 + r) * NDIM + (col0 + j * 16)] =
            fmaf(acc[i][j][r], scale, bj);
      }
    }
  }
}

// ---------------- launch ----------------
extern "C" void kernel_launch(void* const* d_in, const int* in_sizes, int n_in,
                              void* d_out, int out_size, void* d_ws,
                              size_t ws_size, hipStream_t stream) {
  const float* x = (const float*)d_in[0];     // [16384*4096]
  const float* w = (const float*)d_in[1];     // [4096*4096]
  const float* bias = (const float*)d_in[2];  // [4096]
  float* out = (float*)d_out;

  char* ws = (char*)d_ws;
  double* gsum = (double*)ws;                                // 8 B
  short* xb = (short*)(ws + 256);                            // 134 MB
  short* wq = (short*)(ws + 256 + (size_t)MDIM * KDIM * 2);  // 33.5 MB

  const float kHalfF = (float)((pow(2.0, 1.58) - 1.0) * 0.5);  // 0.99484926f

  hipMemsetAsync(gsum, 0, sizeof(double), stream);

  const int nW4 = (NDIM * KDIM) / 4;
  absmean_reduce<<<1024, 256, 0, stream>>>((const float4*)w, gsum, nW4);

  quantize_w<<<4096, 256, 0, stream>>>((const float4*)w, gsum, (ushort4*)wq,
                                       nW4, kHalfF);

  const int nX8 = (MDIM * KDIM) / 8;
  cvt_x<<<8192, 256, 0, stream>>>((const float4*)x, (uint4*)xb, nX8);

  dim3 grid(NDIM / BN, MDIM / BM);  // 32 x 128
  gemm_tern_bf16<<<grid, 256, 0, stream>>>(xb, wq, bias, out, kHalfF);
}